// Round 1
// baseline (213.342 us; speedup 1.0000x reference)
//
#include <hip/hip_runtime.h>

// Problem constants (fixed by setup_inputs)
static constexpr int B     = 16;
static constexpr int L     = 8192;
static constexpr int C     = 256;
static constexpr int C4    = C / 4;        // 64 float4 per row
static constexpr int LOUT  = L / 2;        // 4096 output rows per batch
static constexpr int JPT   = 16;           // output rows per thread
static constexpr int CHUNKS = LOUT / JPT;  // 256 chunks per batch

__device__ __forceinline__ float4 f4max(float4 a, float4 b) {
    return make_float4(fmaxf(a.x, b.x), fmaxf(a.y, b.y),
                       fmaxf(a.z, b.z), fmaxf(a.w, b.w));
}

// z[j] = w0*m[2j-1] + w1*m[2j] + w2*m[2j+1] + w3*m[2j+2]
//   m[l] = max(x[l], x[l+1]) for l < L-1; m[L-1] = x[L-1]; m[-1] = m[L] = 0
__global__ __launch_bounds__(256) void maxblurpool_kernel(
    const float4* __restrict__ x,
    const float*  __restrict__ blur,
    const float*  __restrict__ avg,
    float4*       __restrict__ out)
{
    const int tid   = blockIdx.x * 256 + threadIdx.x;
    const int c4    = tid & (C4 - 1);      // lane -> float4 column (coalesced)
    const int col   = tid >> 6;            // wave-uniform (b, chunk)
    const int chunk = col & (CHUNKS - 1);
    const int b     = col >> 8;            // col / CHUNKS (CHUNKS == 256)

    // Coefficients from the (tiny, uniform) kernel inputs
    const float b0 = blur[0], b1 = blur[1], b2 = blur[2];
    const float a0 = avg[0],  a1 = avg[1];
    const float w0 = a0 * b0;
    const float w1 = a0 * b1 + a1 * b0;
    const float w2 = a0 * b2 + a1 * b1;
    const float w3 = a1 * b2;

    const int  j0 = chunk * JPT;
    const long l0 = 2L * j0;
    const float4* xp = x   + (long)b * L    * C4 + c4;
    float4*       op = out + (long)b * LOUT * C4 + c4;

    // Rolling-window init: m_prev = m[2j0-1], m_cur = m[2j0], x_last = x[2j0+1]
    float4 x_cur  = xp[l0 * C4];
    float4 x_last = xp[(l0 + 1) * C4];
    float4 m_prev;
    if (j0 == 0) {
        m_prev = make_float4(0.f, 0.f, 0.f, 0.f);   // m[-1] = 0 (zero pad)
    } else {
        float4 x_prev = xp[(l0 - 1) * C4];
        m_prev = f4max(x_prev, x_cur);
    }
    float4 m_cur = f4max(x_cur, x_last);

    #pragma unroll
    for (int jj = 0; jj < JPT; ++jj) {
        const int  j  = j0 + jj;
        const long l2 = 2L * j + 2;
        float4 m1, m2, xb;
        if (l2 < L) {                       // wave-uniform branch
            float4 xa = xp[l2 * C4];
            xb        = xp[(l2 + 1) * C4];  // l2 even < L (L even) => l2+1 <= L-1
            m1 = f4max(x_last, xa);
            m2 = f4max(xa, xb);
        } else {                            // only j == LOUT-1: x[L] = -inf, m[L] = 0
            m1 = x_last;                    // max(x[L-1], -inf)
            m2 = make_float4(0.f, 0.f, 0.f, 0.f);
            xb = m2;
        }
        float4 z;
        z.x = w0 * m_prev.x + w1 * m_cur.x + w2 * m1.x + w3 * m2.x;
        z.y = w0 * m_prev.y + w1 * m_cur.y + w2 * m1.y + w3 * m2.y;
        z.z = w0 * m_prev.z + w1 * m_cur.z + w2 * m1.z + w3 * m2.z;
        z.w = w0 * m_prev.w + w1 * m_cur.w + w2 * m1.w + w3 * m2.w;
        op[(long)j * C4] = z;
        m_prev = m1; m_cur = m2; x_last = xb;
    }
}

extern "C" void kernel_launch(void* const* d_in, const int* in_sizes, int n_in,
                              void* d_out, int out_size, void* d_ws, size_t ws_size,
                              hipStream_t stream) {
    const float4* x    = (const float4*)d_in[0];
    const float*  blur = (const float*)d_in[1];
    const float*  avg  = (const float*)d_in[2];
    float4*       out  = (float4*)d_out;

    const int total_threads = B * CHUNKS * C4;  // 262144
    const int block = 256;
    const int grid  = total_threads / block;    // 1024 blocks -> 4 blocks/CU
    maxblurpool_kernel<<<grid, block, 0, stream>>>(x, blur, avg, out);
}

// Round 2
// 209.700 us; speedup vs baseline: 1.0174x; 1.0174x over previous
//
#include <hip/hip_runtime.h>

// Problem constants (fixed by setup_inputs)
static constexpr int B     = 16;
static constexpr int L     = 8192;
static constexpr int C     = 256;
static constexpr int C4    = C / 4;        // 64 float4 per row
static constexpr int LOUT  = L / 2;        // 4096 output rows per batch
static constexpr int PAIRS = LOUT / 2;     // 2048 output-row pairs per batch

__device__ __forceinline__ float4 f4max(float4 a, float4 b) {
    return make_float4(fmaxf(a.x, b.x), fmaxf(a.y, b.y),
                       fmaxf(a.z, b.z), fmaxf(a.w, b.w));
}

// z[j] = w0*m[2j-1] + w1*m[2j] + w2*m[2j+1] + w3*m[2j+2]
//   m[l] = max(x[l], x[l+1]) for l < L-1; m[L-1] = x[L-1]; m[-1] = m[L] = 0
// Branch-free: one thread computes outputs {j, j+1} (j even) for one float4
// column. 7 independent loads (rows 2j-1 .. 2j+5, clamped), edge semantics
// via clamped indices + zeroed edge weights. No loops, no divergence.
__global__ __launch_bounds__(256) void maxblurpool_kernel(
    const float4* __restrict__ x,
    const float*  __restrict__ blur,
    const float*  __restrict__ avg,
    float4*       __restrict__ out)
{
    const int t  = blockIdx.x * 256 + threadIdx.x;
    const int c4 = t & (C4 - 1);           // lane -> float4 column (coalesced)
    const int p  = t >> 6;                 // wave-uniform pair index
    const int b  = p >> 11;                // p / PAIRS   (PAIRS == 2048)
    const int pj = p & (PAIRS - 1);
    const int j  = pj << 1;                // first output row (even)
    const int i  = j << 1;                 // center input row; i+3 <= L-1 always

    // Coefficients (uniform)
    const float b0 = blur[0], b1 = blur[1], b2 = blur[2];
    const float a0 = avg[0],  a1 = avg[1];
    const float w0 = a0 * b0;
    const float w1 = a0 * b1 + a1 * b0;
    const float w2 = a0 * b2 + a1 * b1;
    const float w3 = a1 * b2;
    const float w0a = (j == 0)        ? 0.f : w0;  // m[-1] = 0
    const float w3b = (j + 1 == LOUT - 1) ? 0.f : w3;  // m[L] = 0

    const float4* xp = x   + (long)b * L    * C4 + c4;
    float4*       op = out + (long)b * LOUT * C4 + c4;

    // Clamped row indices (only first/last pair actually clamp)
    const int rm1 = (i > 0)         ? i - 1 : 0;
    const int r4  = (i + 4 <= L - 1) ? i + 4 : L - 1;
    const int r5  = (i + 5 <= L - 1) ? i + 5 : L - 1;

    // 7 independent loads — all issued before any use
    const float4 xm1 = xp[(long)rm1     * C4];
    const float4 x0  = xp[(long)i       * C4];
    const float4 x1  = xp[(long)(i + 1) * C4];
    const float4 x2  = xp[(long)(i + 2) * C4];
    const float4 x3  = xp[(long)(i + 3) * C4];
    const float4 x4  = xp[(long)r4      * C4];
    const float4 x5  = xp[(long)r5      * C4];

    const float4 m0 = f4max(xm1, x0);  // m[2j-1] (w0a kills it at j==0)
    const float4 m1 = f4max(x0,  x1);  // m[2j]
    const float4 m2 = f4max(x1,  x2);  // m[2j+1]   == m[2(j+1)-1]
    const float4 m3 = f4max(x2,  x3);  // m[2j+2]   == m[2(j+1)]
    const float4 m4 = f4max(x3,  x4);  // m[2j+3]; clamp makes this m[L-1]=x[L-1] at the end
    const float4 m5 = f4max(x4,  x5);  // m[2j+4] (w3b kills it at j+1==LOUT-1)

    float4 za, zb;
    za.x = w0a * m0.x + w1 * m1.x + w2 * m2.x + w3  * m3.x;
    za.y = w0a * m0.y + w1 * m1.y + w2 * m2.y + w3  * m3.y;
    za.z = w0a * m0.z + w1 * m1.z + w2 * m2.z + w3  * m3.z;
    za.w = w0a * m0.w + w1 * m1.w + w2 * m2.w + w3  * m3.w;
    zb.x = w0  * m2.x + w1 * m3.x + w2 * m4.x + w3b * m5.x;
    zb.y = w0  * m2.y + w1 * m3.y + w2 * m4.y + w3b * m5.y;
    zb.z = w0  * m2.z + w1 * m3.z + w2 * m4.z + w3b * m5.z;
    zb.w = w0  * m2.w + w1 * m3.w + w2 * m4.w + w3b * m5.w;

    op[(long)j       * C4] = za;
    op[(long)(j + 1) * C4] = zb;
}

extern "C" void kernel_launch(void* const* d_in, const int* in_sizes, int n_in,
                              void* d_out, int out_size, void* d_ws, size_t ws_size,
                              hipStream_t stream) {
    const float4* x    = (const float4*)d_in[0];
    const float*  blur = (const float*)d_in[1];
    const float*  avg  = (const float*)d_in[2];
    float4*       out  = (float4*)d_out;

    const int total_threads = B * PAIRS * C4;   // 2,097,152
    const int block = 256;
    const int grid  = total_threads / block;    // 8192 blocks
    maxblurpool_kernel<<<grid, block, 0, stream>>>(x, blur, avg, out);
}